// Round 3
// baseline (961.937 us; speedup 1.0000x reference)
//
#include <hip/hip_runtime.h>
#include <math.h>

#define NN 100000
#define NE 1000000
#define NR 1000
#define DD 100
#define OUTC 600
#define EPS 1e-12f
#define NBIN 64
#define RESCALE_THR 8.0f

__device__ inline float wave_sum(float v) {
#pragma unroll
    for (int o = 32; o > 0; o >>= 1) v += __shfl_down(v, o, 64);
    return __shfl(v, 0, 64);
}
// sum across the 4 lanes of a quad (lane bits 0..1); broadcast within quad
__device__ inline float quad_sum(float v) {
    v += __shfl_xor(v, 1, 64);
    v += __shfl_xor(v, 2, 64);
    return v;
}

// row_ptr[n] = lower_bound(dst, n); dst sorted ascending. row_ptr[NN] = NE.
// Also zeroes the degree histogram (used by the sort kernels below).
__global__ void k_rowptr(const int* __restrict__ dst, int* __restrict__ row_ptr,
                         int* __restrict__ ghist) {
    int n = blockIdx.x * blockDim.x + threadIdx.x;
    if (n < NBIN) ghist[n] = 0;
    if (n > NN) return;
    int lo = 0, hi = NE;
    while (lo < hi) {
        int mid = (lo + hi) >> 1;
        if (dst[mid] < n) lo = mid + 1; else hi = mid;
    }
    row_ptr[n] = lo;
}

// ---- degree counting sort: nodes with similar degree become adjacent in perm,
// so the 16 node-groups of a wave run near-equal edge loops (no max-of-16 tax).
__global__ void k_hist(const int* __restrict__ row_ptr, int* __restrict__ ghist) {
    __shared__ int lh[NBIN];
    int t = threadIdx.x;
    if (t < NBIN) lh[t] = 0;
    __syncthreads();
    int n = blockIdx.x * blockDim.x + t;
    if (n < NN) {
        int d = row_ptr[n + 1] - row_ptr[n];
        atomicAdd(&lh[min(d, NBIN - 1)], 1);
    }
    __syncthreads();
    if (t < NBIN && lh[t]) atomicAdd(&ghist[t], lh[t]);
}
__global__ void k_scan(const int* __restrict__ ghist, int* __restrict__ goffs) {
    if (threadIdx.x == 0) {
        int s = 0;
        for (int i = 0; i < NBIN; ++i) { goffs[i] = s; s += ghist[i]; }
    }
}
__global__ void k_scatter(const int* __restrict__ row_ptr, int* __restrict__ goffs,
                          int* __restrict__ perm) {
    __shared__ int lh[NBIN], base[NBIN];
    int t = threadIdx.x;
    if (t < NBIN) lh[t] = 0;
    __syncthreads();
    int n = blockIdx.x * blockDim.x + t;
    int bin = 0, rank = 0;
    if (n < NN) {
        int d = row_ptr[n + 1] - row_ptr[n];
        bin = min(d, NBIN - 1);
        rank = atomicAdd(&lh[bin], 1);
    }
    __syncthreads();
    if (t < NBIN && lh[t]) base[t] = atomicAdd(&goffs[t], lh[t]);
    __syncthreads();
    if (n < NN) perm[base[bin] + rank] = n;
}

// rel_norm[r] = rel_emb[r] / max(||rel_emb[r]||, EPS); one wave per relation
__global__ void k_relnorm(const float* __restrict__ rel_emb, float* __restrict__ rel_norm) {
    int w = (blockIdx.x * blockDim.x + threadIdx.x) >> 6;
    int lane = threadIdx.x & 63;
    if (w >= NR) return;
    const float* r = rel_emb + w * DD;
    float v0 = r[lane];
    float v1 = (lane + 64 < DD) ? r[lane + 64] : 0.f;
    float ss = wave_sum(v0 * v0 + v1 * v1);
    float sc = 1.f / fmaxf(sqrtf(ss), EPS);
    float* o = rel_norm + w * DD;
    o[lane] = v0 * sc;
    if (lane + 64 < DD) o[lane + 64] = v1 * sc;
}

// per-relation dots: rdot[r] = <rel_norm[r], w_r>, rwn[r] = <rel_norm[r], w_n>
__global__ void k_relv(const float* __restrict__ rel_norm, const float* __restrict__ k3d,
                       float* __restrict__ rdot, float* __restrict__ rwn) {
    int w = (blockIdx.x * blockDim.x + threadIdx.x) >> 6;
    int lane = threadIdx.x & 63;
    if (w >= NR) return;
    const float* r = rel_norm + w * DD;
    float r0 = r[lane];
    float r1 = (lane + 64 < DD) ? r[lane + 64] : 0.f;
    float wr1 = 0.f, wn1 = 0.f;
    float wr0 = k3d[2 * DD + lane], wn0 = k3d[DD + lane];
    if (lane + 64 < DD) { wr1 = k3d[2 * DD + lane + 64]; wn1 = k3d[DD + lane + 64]; }
    float rd = wave_sum(r0 * wr0 + r1 * wr1);
    float rn = wave_sum(r0 * wn0 + r1 * wn1);
    if (lane == 0) { rdot[w] = rd; rwn[w] = rn; }
}

// tanh(segment-mean) — one NODE per 4-lane group (25 dims/lane: 6xfloat4 + 1).
// Pure register accumulation, zero LDS, zero cross-group traffic. Nodes taken
// in degree-sorted order (perm) so all 16 groups of a wave loop ~equally.
// Fuses the layer-0 node dots into the epilogue.
__global__ __launch_bounds__(256) void k_segmean(
        const float* __restrict__ table, const int* __restrict__ idx,
        const int* __restrict__ row_ptr, const int* __restrict__ perm,
        const float* __restrict__ k3d,
        float* __restrict__ sdot, float* __restrict__ ndot,
        float* __restrict__ F, long long fstride,
        float* __restrict__ outcol, int dup) {
    int gi = (blockIdx.x * blockDim.x + threadIdx.x) >> 2;
    int sb = threadIdx.x & 3;
    if (gi >= NN) return;
    int n = perm[gi];
    int beg = row_ptr[n], end = row_ptr[n + 1];
    float4 acc[6] = {};
    float acct = 0.f;
    for (int e = beg; e < end; ++e) {
        int t = idx[e];
        const float4* r4 = (const float4*)(table + (size_t)t * DD);
#pragma unroll
        for (int k = 0; k < 6; ++k) {
            float4 v = r4[4 * k + sb];
            acc[k].x += v.x; acc[k].y += v.y; acc[k].z += v.z; acc[k].w += v.w;
        }
        acct += ((const float*)r4)[96 + sb];
    }
    float inv = 1.f / fmaxf((float)(end - beg), 1.f);
    float4 o4[6]; float ot;
#pragma unroll
    for (int k = 0; k < 6; ++k) {
        o4[k].x = tanhf(acc[k].x * inv);
        o4[k].y = tanhf(acc[k].y * inv);
        o4[k].z = tanhf(acc[k].z * inv);
        o4[k].w = tanhf(acc[k].w * inv);
    }
    ot = tanhf(acct * inv);
    float* fo = F + (size_t)n * fstride;
    float4* fo4 = (float4*)fo;
#pragma unroll
    for (int k = 0; k < 6; ++k) fo4[4 * k + sb] = o4[k];
    fo[96 + sb] = ot;
    if (dup) {
        float* oc = outcol + (size_t)n * OUTC;
        float4* oc4 = (float4*)oc;
#pragma unroll
        for (int k = 0; k < 6; ++k) oc4[4 * k + sb] = o4[k];
        oc[96 + sb] = ot;
    }
    // fused node dots (layer 0)
    const float4* w4 = (const float4*)k3d;
    float sp = ot * k3d[96 + sb];
    float np = ot * k3d[DD + 96 + sb];
#pragma unroll
    for (int k = 0; k < 6; ++k) {
        float4 ws = w4[4 * k + sb];
        float4 wn = w4[25 + 4 * k + sb];
        sp += o4[k].x * ws.x + o4[k].y * ws.y + o4[k].z * ws.z + o4[k].w * ws.w;
        np += o4[k].x * wn.x + o4[k].y * wn.y + o4[k].z * wn.z + o4[k].w * wn.w;
    }
    float sdv = quad_sum(sp);
    float ndv = quad_sum(np);
    if (sb == 0) { sdot[n] = sdv; ndot[n] = ndv; }
}

// Fused layer — one NODE per 4-lane group, edges walked serially per group.
// Per edge: gather F[src]/rel_norm[erel] slices (registers), quad-dot (2
// shuffles), defer-max online softmax (rescale only when the running max
// grows by >THR), and register accumulation of w*(f - c*r). No LDS at all.
// Optionally fuses the next layer's node dots (separate out-buffers since
// concurrent waves still read this layer's ndot).
__global__ __launch_bounds__(256) void k_layer(
        const float* __restrict__ F, long long fstride,
        const float* __restrict__ rel_norm,
        const int* __restrict__ src, const int* __restrict__ erel,
        const int* __restrict__ row_ptr, const int* __restrict__ perm,
        const float* __restrict__ sdot, const float* __restrict__ ndot,
        const float* __restrict__ rdot, const float* __restrict__ rwn,
        const float* __restrict__ k3d_next,
        float* __restrict__ sdot_o, float* __restrict__ ndot_o,
        float* __restrict__ Fnext, long long fnstride,
        float* __restrict__ outcol, int dup) {
    int gi = (blockIdx.x * blockDim.x + threadIdx.x) >> 2;
    int sb = threadIdx.x & 3;
    if (gi >= NN) return;
    int n = perm[gi];
    int beg = row_ptr[n], end = row_ptr[n + 1];
    float sd = sdot[n];
    float4 acc[6] = {};
    float acct = 0.f;
    float m_run = -INFINITY, l_run = 0.f;
    for (int e = beg; e < end; ++e) {
        int s_e = src[e];
        int r_e = erel[e];
        const float4* f4 = (const float4*)(F + (size_t)s_e * fstride);
        const float4* r4 = (const float4*)(rel_norm + (size_t)r_e * DD);
        float nd = ndot[s_e], rd = rdot[r_e], rw = rwn[r_e];
        float4 fv[6], rv[6];
#pragma unroll
        for (int k = 0; k < 6; ++k) { fv[k] = f4[4 * k + sb]; rv[k] = r4[4 * k + sb]; }
        float ft = ((const float*)f4)[96 + sb];
        float rt = ((const float*)r4)[96 + sb];
        float p0 = ft * rt, p1 = 0.f, p2 = 0.f, p3 = 0.f;
#pragma unroll
        for (int k = 0; k < 6; ++k) {
            p0 += fv[k].x * rv[k].x;
            p1 += fv[k].y * rv[k].y;
            p2 += fv[k].z * rv[k].z;
            p3 += fv[k].w * rv[k].w;
        }
        float p = (p0 + p1) + (p2 + p3);
        p += __shfl_xor(p, 1, 64);
        p += __shfl_xor(p, 2, 64);                 // group-uniform dot
        float c = 2.f * p;
        float lg = sd + nd - c * rw + rd;          // group-uniform logit
        float w;
        if (lg > m_run + RESCALE_THR) {            // rebase (rare after warmup)
            float sc = __expf(m_run - lg);         // 0 on first edge
            l_run *= sc; acct *= sc;
#pragma unroll
            for (int k = 0; k < 6; ++k) {
                acc[k].x *= sc; acc[k].y *= sc; acc[k].z *= sc; acc[k].w *= sc;
            }
            m_run = lg;
            w = 1.f;
        } else {
            w = __expf(lg - m_run);                // bounded by e^THR
        }
        l_run += w;
        float wc = w * c;
#pragma unroll
        for (int k = 0; k < 6; ++k) {
            acc[k].x += w * fv[k].x - wc * rv[k].x;
            acc[k].y += w * fv[k].y - wc * rv[k].y;
            acc[k].z += w * fv[k].z - wc * rv[k].z;
            acc[k].w += w * fv[k].w - wc * rv[k].w;
        }
        acct += w * ft - wc * rt;
    }
    float inv = (end > beg) ? (1.f / l_run) : 0.f;
    float4 o4[6]; float ot;
#pragma unroll
    for (int k = 0; k < 6; ++k) {
        o4[k].x = tanhf(acc[k].x * inv);
        o4[k].y = tanhf(acc[k].y * inv);
        o4[k].z = tanhf(acc[k].z * inv);
        o4[k].w = tanhf(acc[k].w * inv);
    }
    ot = tanhf(acct * inv);
    float* fo = Fnext + (size_t)n * fnstride;
    float4* fo4 = (float4*)fo;
#pragma unroll
    for (int k = 0; k < 6; ++k) fo4[4 * k + sb] = o4[k];
    fo[96 + sb] = ot;
    if (dup) {
        float* oc = outcol + (size_t)n * OUTC;
        float4* oc4 = (float4*)oc;
#pragma unroll
        for (int k = 0; k < 6; ++k) oc4[4 * k + sb] = o4[k];
        oc[96 + sb] = ot;
    }
    if (k3d_next) {
        const float4* w4 = (const float4*)k3d_next;
        float sp = ot * k3d_next[96 + sb];
        float np = ot * k3d_next[DD + 96 + sb];
#pragma unroll
        for (int k = 0; k < 6; ++k) {
            float4 ws = w4[4 * k + sb];
            float4 wn = w4[25 + 4 * k + sb];
            sp += o4[k].x * ws.x + o4[k].y * ws.y + o4[k].z * ws.z + o4[k].w * ws.w;
            np += o4[k].x * wn.x + o4[k].y * wn.y + o4[k].z * wn.z + o4[k].w * wn.w;
        }
        float sdv = quad_sum(sp);
        float ndv = quad_sum(np);
        if (sb == 0) { sdot_o[n] = sdv; ndot_o[n] = ndv; }
    }
}

extern "C" void kernel_launch(void* const* d_in, const int* in_sizes, int n_in,
                              void* d_out, int out_size, void* d_ws, size_t ws_size,
                              hipStream_t stream) {
    const float* ent_emb = (const float*)d_in[0];
    const float* rel_emb = (const float*)d_in[1];
    const float* attn_e  = (const float*)d_in[2];
    const float* attn_r  = (const float*)d_in[3];
    const int*   src     = (const int*)d_in[4];
    const int*   dst     = (const int*)d_in[5];
    const int*   erel    = (const int*)d_in[6];
    float* out = (float*)d_out;

    char* ws = (char*)d_ws;
    size_t off = 0;
    auto alloc = [&](size_t bytes) -> void* {
        void* p = ws + off;
        off = (off + bytes + 255) & ~(size_t)255;
        return p;
    };
    int*   row_ptr  = (int*)alloc((NN + 1) * sizeof(int));
    float* rel_norm = (float*)alloc((size_t)NR * DD * sizeof(float));
    float* sdotA    = (float*)alloc(NN * sizeof(float));
    float* ndotA    = (float*)alloc(NN * sizeof(float));
    float* sdotB    = (float*)alloc(NN * sizeof(float));
    float* ndotB    = (float*)alloc(NN * sizeof(float));
    float* rdot     = (float*)alloc(NR * sizeof(float));
    float* rwn      = (float*)alloc(NR * sizeof(float));
    int*   ghist    = (int*)alloc(NBIN * sizeof(int));
    int*   goffs    = (int*)alloc(NBIN * sizeof(int));
    int*   perm     = (int*)alloc(NN * sizeof(int));
    float* featsA   = (float*)alloc((size_t)NN * DD * sizeof(float));
    float* featsB   = (float*)alloc((size_t)NN * DD * sizeof(float));
    bool compact = (off <= ws_size);

    hipLaunchKernelGGL(k_rowptr, dim3((NN + 256) / 256), dim3(256), 0, stream,
                       dst, row_ptr, ghist);
    hipLaunchKernelGGL(k_hist, dim3((NN + 255) / 256), dim3(256), 0, stream, row_ptr, ghist);
    hipLaunchKernelGGL(k_scan, dim3(1), dim3(64), 0, stream, ghist, goffs);
    hipLaunchKernelGGL(k_scatter, dim3((NN + 255) / 256), dim3(256), 0, stream,
                       row_ptr, goffs, perm);
    hipLaunchKernelGGL(k_relnorm, dim3(NR * 64 / 256), dim3(256), 0, stream, rel_emb, rel_norm);

    const int NODE_BLOCKS = (NN + 63) / 64;   // 64 node-groups per 256-thread block

    for (int enc = 0; enc < 2; ++enc) {
        const float* attn = (enc == 0) ? attn_e : attn_r;
        const float* table = (enc == 0) ? ent_emb : rel_emb;
        const int*   idx   = (enc == 0) ? src : erel;
        int colbase = enc * 300;

        float* F; long long fs;
        if (compact) { F = featsA; fs = DD; }
        else         { F = out + colbase; fs = OUTC; }
        hipLaunchKernelGGL(k_segmean, dim3(NODE_BLOCKS), dim3(256), 0, stream,
                           table, idx, row_ptr, perm, attn /*layer-0 weights*/,
                           sdotA, ndotA, F, fs,
                           compact ? (out + colbase) : (float*)nullptr, compact ? 1 : 0);

        for (int l = 0; l < 2; ++l) {
            int colO = colbase + (l + 1) * 100;
            const float* k3d = attn + l * 300;
            const float* k3d_next = (l == 0) ? (attn + 300) : (const float*)nullptr;
            const float* sd_in = (l == 0) ? sdotA : sdotB;
            const float* nd_in = (l == 0) ? ndotA : ndotB;
            hipLaunchKernelGGL(k_relv, dim3(NR * 64 / 256), dim3(256), 0, stream,
                               rel_norm, k3d, rdot, rwn);
            float* Fn; long long fns;
            if (compact) { Fn = (l == 0) ? featsB : featsA; fns = DD; }
            else         { Fn = out + colO; fns = OUTC; }
            hipLaunchKernelGGL(k_layer, dim3(NODE_BLOCKS), dim3(256), 0, stream,
                               F, fs, rel_norm, src, erel, row_ptr, perm,
                               sd_in, nd_in, rdot, rwn,
                               k3d_next, sdotB, ndotB,
                               Fn, fns,
                               compact ? (out + colO) : (float*)nullptr, compact ? 1 : 0);
            F = Fn; fs = fns;
        }
    }
}

// Round 5
// 916.684 us; speedup vs baseline: 1.0494x; 1.0494x over previous
//
#include <hip/hip_runtime.h>
#include <hip/hip_fp16.h>
#include <math.h>

#define NN 100000
#define NE 1000000
#define NR 1000
#define DD 100
#define HS 104          // fp16 feature-row stride: 208 B = 16B-aligned, exactly 4 cache lines
#define OUTC 600
#define EPS 1e-12f
#define NBIN 64
#define RESCALE_THR 8.0f

struct __attribute__((aligned(16))) h8 { unsigned short u[8]; };

__device__ inline float h2f(unsigned short u) {
    __half_raw r; r.x = u; __half h = r; return __half2float(h);
}
__device__ inline unsigned short f2h(float f) {
    __half h = __float2half_rn(f); __half_raw r = h; return r.x;
}

__device__ inline float wave_sum(float v) {
#pragma unroll
    for (int o = 32; o > 0; o >>= 1) v += __shfl_down(v, o, 64);
    return __shfl(v, 0, 64);
}
// sum across the 4 lanes of a quad (lane bits 0..1); broadcast within quad
__device__ inline float quad_sum(float v) {
    v += __shfl_xor(v, 1, 64);
    v += __shfl_xor(v, 2, 64);
    return v;
}

// row_ptr[n] = lower_bound(dst, n); dst sorted ascending. row_ptr[NN] = NE.
__global__ void k_rowptr(const int* __restrict__ dst, int* __restrict__ row_ptr,
                         int* __restrict__ ghist) {
    int n = blockIdx.x * blockDim.x + threadIdx.x;
    if (n < NBIN) ghist[n] = 0;
    if (n > NN) return;
    int lo = 0, hi = NE;
    while (lo < hi) {
        int mid = (lo + hi) >> 1;
        if (dst[mid] < n) lo = mid + 1; else hi = mid;
    }
    row_ptr[n] = lo;
}

// ---- degree counting sort: nodes with similar degree become adjacent in perm.
__global__ void k_hist(const int* __restrict__ row_ptr, int* __restrict__ ghist) {
    __shared__ int lh[NBIN];
    int t = threadIdx.x;
    if (t < NBIN) lh[t] = 0;
    __syncthreads();
    int n = blockIdx.x * blockDim.x + t;
    if (n < NN) {
        int d = row_ptr[n + 1] - row_ptr[n];
        atomicAdd(&lh[min(d, NBIN - 1)], 1);
    }
    __syncthreads();
    if (t < NBIN && lh[t]) atomicAdd(&ghist[t], lh[t]);
}
__global__ void k_scan(const int* __restrict__ ghist, int* __restrict__ goffs) {
    if (threadIdx.x == 0) {
        int s = 0;
        for (int i = 0; i < NBIN; ++i) { goffs[i] = s; s += ghist[i]; }
    }
}
__global__ void k_scatter(const int* __restrict__ row_ptr, int* __restrict__ goffs,
                          int* __restrict__ perm) {
    __shared__ int lh[NBIN], base[NBIN];
    int t = threadIdx.x;
    if (t < NBIN) lh[t] = 0;
    __syncthreads();
    int n = blockIdx.x * blockDim.x + t;
    int bin = 0, rank = 0;
    if (n < NN) {
        int d = row_ptr[n + 1] - row_ptr[n];
        bin = min(d, NBIN - 1);
        rank = atomicAdd(&lh[bin], 1);
    }
    __syncthreads();
    if (t < NBIN && lh[t]) base[t] = atomicAdd(&goffs[t], lh[t]);
    __syncthreads();
    if (n < NN) perm[base[bin] + rank] = n;
}

// rel_norm[r] = rel_emb[r] / max(||rel_emb[r]||, EPS); one wave per relation
__global__ void k_relnorm(const float* __restrict__ rel_emb, float* __restrict__ rel_norm) {
    int w = (blockIdx.x * blockDim.x + threadIdx.x) >> 6;
    int lane = threadIdx.x & 63;
    if (w >= NR) return;
    const float* r = rel_emb + w * DD;
    float v0 = r[lane];
    float v1 = (lane + 64 < DD) ? r[lane + 64] : 0.f;
    float ss = wave_sum(v0 * v0 + v1 * v1);
    float sc = 1.f / fmaxf(sqrtf(ss), EPS);
    float* o = rel_norm + w * DD;
    o[lane] = v0 * sc;
    if (lane + 64 < DD) o[lane + 64] = v1 * sc;
}

// per-relation dots: rdot[r] = <rel_norm[r], w_r>, rwn[r] = <rel_norm[r], w_n>
__global__ void k_relv(const float* __restrict__ rel_norm, const float* __restrict__ k3d,
                       float* __restrict__ rdot, float* __restrict__ rwn) {
    int w = (blockIdx.x * blockDim.x + threadIdx.x) >> 6;
    int lane = threadIdx.x & 63;
    if (w >= NR) return;
    const float* r = rel_norm + w * DD;
    float r0 = r[lane];
    float r1 = (lane + 64 < DD) ? r[lane + 64] : 0.f;
    float wr1 = 0.f, wn1 = 0.f;
    float wr0 = k3d[2 * DD + lane], wn0 = k3d[DD + lane];
    if (lane + 64 < DD) { wr1 = k3d[2 * DD + lane + 64]; wn1 = k3d[DD + lane + 64]; }
    float rd = wave_sum(r0 * wr0 + r1 * wr1);
    float rn = wave_sum(r0 * wn0 + r1 * wn1);
    if (lane == 0) { rdot[w] = rd; rwn[w] = rn; }
}

// f32 row (DD floats) -> fp16 row (HS halves), blocked 24-per-lane + tail layout
__global__ void k_tohalf(const float* __restrict__ s, unsigned short* __restrict__ d, int rows) {
    int gi = blockIdx.x * blockDim.x + threadIdx.x;
    int n = gi >> 2, sb = gi & 3;
    if (n >= rows) return;
    const float4* s4 = (const float4*)(s + (size_t)n * DD);
    unsigned short* dr = d + (size_t)n * HS;
#pragma unroll
    for (int j = 0; j < 3; ++j) {
        float4 a = s4[6 * sb + 2 * j];
        float4 b = s4[6 * sb + 2 * j + 1];
        h8 o;
        o.u[0] = f2h(a.x); o.u[1] = f2h(a.y); o.u[2] = f2h(a.z); o.u[3] = f2h(a.w);
        o.u[4] = f2h(b.x); o.u[5] = f2h(b.y); o.u[6] = f2h(b.z); o.u[7] = f2h(b.w);
        ((h8*)(dr + 24 * sb))[j] = o;
    }
    dr[96 + sb] = f2h(s[(size_t)n * DD + 96 + sb]);
}

// ---- blocked dim->lane mapping used below: lane sb owns dims [24sb..24sb+23]
// (o[0..23]) plus tail dim 96+sb (o[24]). Consistent across gather/acc/store/dots.

// tanh(segment-mean) — one NODE per 4-lane group, register accumulation, no LDS.
// FH=1: table is fp16 rows (HS stride, 4 cache lines/row); FH=0: f32 rows (DD).
// Fuses the layer-0 node dots into the epilogue.
template<int FH>
__global__ __launch_bounds__(256) void k_segmean(
        const void* __restrict__ table, const int* __restrict__ idx,
        const int* __restrict__ row_ptr, const int* __restrict__ perm,
        const float* __restrict__ k3d,
        float* __restrict__ sdot, float* __restrict__ ndot,
        void* __restrict__ Fout, long long fstride,
        float* __restrict__ outcol, int dup) {
    int gi = (blockIdx.x * blockDim.x + threadIdx.x) >> 2;
    int sb = threadIdx.x & 3;
    if (gi >= NN) return;
    int n = perm[gi];
    int beg = row_ptr[n], end = row_ptr[n + 1];
    float acc[25] = {};
    for (int e = beg; e < end; ++e) {
        int t = idx[e];
        if (FH) {
            const unsigned short* row = (const unsigned short*)table + (size_t)t * HS;
            const h8* r8 = (const h8*)(row + 24 * sb);
            h8 ha = r8[0], hb = r8[1], hc = r8[2];
#pragma unroll
            for (int m = 0; m < 8; ++m) {
                acc[m]      += h2f(ha.u[m]);
                acc[8 + m]  += h2f(hb.u[m]);
                acc[16 + m] += h2f(hc.u[m]);
            }
            acc[24] += h2f(row[96 + sb]);
        } else {
            const float* row = (const float*)table + (size_t)t * DD;
            const float4* r4 = (const float4*)row;
#pragma unroll
            for (int k = 0; k < 6; ++k) {
                float4 v = r4[6 * sb + k];
                acc[4 * k] += v.x; acc[4 * k + 1] += v.y;
                acc[4 * k + 2] += v.z; acc[4 * k + 3] += v.w;
            }
            acc[24] += row[96 + sb];
        }
    }
    float inv = 1.f / fmaxf((float)(end - beg), 1.f);
    float o[25];
#pragma unroll
    for (int m = 0; m < 25; ++m) o[m] = tanhf(acc[m] * inv);
    if (FH) {
        unsigned short* fr = (unsigned short*)Fout + (size_t)n * HS;
#pragma unroll
        for (int j = 0; j < 3; ++j) {
            h8 hx;
#pragma unroll
            for (int m = 0; m < 8; ++m) hx.u[m] = f2h(o[8 * j + m]);
            ((h8*)(fr + 24 * sb))[j] = hx;
        }
        fr[96 + sb] = f2h(o[24]);
    } else {
        float* fr = (float*)Fout + (size_t)n * fstride;
        float4* f4o = (float4*)fr;
#pragma unroll
        for (int k = 0; k < 6; ++k) {
            float4 v = { o[4 * k], o[4 * k + 1], o[4 * k + 2], o[4 * k + 3] };
            f4o[6 * sb + k] = v;
        }
        fr[96 + sb] = o[24];
    }
    if (dup) {
        float* oc = outcol + (size_t)n * OUTC;
        float4* oc4 = (float4*)oc;
#pragma unroll
        for (int k = 0; k < 6; ++k) {
            float4 v = { o[4 * k], o[4 * k + 1], o[4 * k + 2], o[4 * k + 3] };
            oc4[6 * sb + k] = v;
        }
        oc[96 + sb] = o[24];
    }
    // fused node dots (layer 0)
    const float4* w4s = (const float4*)k3d;
    const float4* w4n = (const float4*)(k3d + DD);
    float sp = o[24] * k3d[96 + sb];
    float np = o[24] * k3d[DD + 96 + sb];
#pragma unroll
    for (int k = 0; k < 6; ++k) {
        float4 ws = w4s[6 * sb + k];
        float4 wn = w4n[6 * sb + k];
        sp += o[4 * k] * ws.x + o[4 * k + 1] * ws.y + o[4 * k + 2] * ws.z + o[4 * k + 3] * ws.w;
        np += o[4 * k] * wn.x + o[4 * k + 1] * wn.y + o[4 * k + 2] * wn.z + o[4 * k + 3] * wn.w;
    }
    float sdv = quad_sum(sp);
    float ndv = quad_sum(np);
    if (sb == 0) { sdot[n] = sdv; ndot[n] = ndv; }
}

// Fused layer — one NODE per 4-lane group, edges serial per group, register
// accumulation, defer-max online softmax. FH=1: F gathered as fp16 (4 lines/row
// instead of 7 — the L2-miss-path lever); rel_norm stays f32 (L2-resident).
template<int FH>
__global__ __launch_bounds__(256) void k_layer(
        const void* __restrict__ F, long long fstride,
        const float* __restrict__ rel_norm,
        const int* __restrict__ src, const int* __restrict__ erel,
        const int* __restrict__ row_ptr, const int* __restrict__ perm,
        const float* __restrict__ sdot, const float* __restrict__ ndot,
        const float* __restrict__ rdot, const float* __restrict__ rwn,
        const float* __restrict__ k3d_next,
        float* __restrict__ sdot_o, float* __restrict__ ndot_o,
        void* __restrict__ Fnext, long long fnstride,
        float* __restrict__ outcol, int dup) {
    int gi = (blockIdx.x * blockDim.x + threadIdx.x) >> 2;
    int sb = threadIdx.x & 3;
    if (gi >= NN) return;
    int n = perm[gi];
    int beg = row_ptr[n], end = row_ptr[n + 1];
    float sd = sdot[n];
    float acc[25] = {};
    float m_run = -INFINITY, l_run = 0.f;
    for (int e = beg; e < end; ++e) {
        int s_e = src[e];
        int r_e = erel[e];
        float nd = ndot[s_e], rd = rdot[r_e], rw = rwn[r_e];
        float fv[25], rv[25];
        if (FH) {
            const unsigned short* frow = (const unsigned short*)F + (size_t)s_e * HS;
            const h8* f8 = (const h8*)(frow + 24 * sb);
            h8 ha = f8[0], hb = f8[1], hc = f8[2];
#pragma unroll
            for (int m = 0; m < 8; ++m) {
                fv[m]      = h2f(ha.u[m]);
                fv[8 + m]  = h2f(hb.u[m]);
                fv[16 + m] = h2f(hc.u[m]);
            }
            fv[24] = h2f(frow[96 + sb]);
        } else {
            const float* frow = (const float*)F + (size_t)s_e * fstride;
            const float4* f4 = (const float4*)frow;
#pragma unroll
            for (int k = 0; k < 6; ++k) {
                float4 v = f4[6 * sb + k];
                fv[4 * k] = v.x; fv[4 * k + 1] = v.y; fv[4 * k + 2] = v.z; fv[4 * k + 3] = v.w;
            }
            fv[24] = frow[96 + sb];
        }
        const float* rrow = rel_norm + (size_t)r_e * DD;
        const float4* r4 = (const float4*)rrow;
#pragma unroll
        for (int k = 0; k < 6; ++k) {
            float4 v = r4[6 * sb + k];
            rv[4 * k] = v.x; rv[4 * k + 1] = v.y; rv[4 * k + 2] = v.z; rv[4 * k + 3] = v.w;
        }
        rv[24] = rrow[96 + sb];
        float p0 = fv[24] * rv[24], p1 = 0.f, p2 = 0.f, p3 = 0.f;
#pragma unroll
        for (int m = 0; m < 24; m += 4) {
            p0 += fv[m] * rv[m];
            p1 += fv[m + 1] * rv[m + 1];
            p2 += fv[m + 2] * rv[m + 2];
            p3 += fv[m + 3] * rv[m + 3];
        }
        float p = (p0 + p1) + (p2 + p3);
        p += __shfl_xor(p, 1, 64);
        p += __shfl_xor(p, 2, 64);                 // group-uniform dot
        float c = 2.f * p;
        float lg = sd + nd - c * rw + rd;          // group-uniform logit
        float w;
        if (lg > m_run + RESCALE_THR) {            // rebase (rare after warmup)
            float sc = __expf(m_run - lg);         // 0 on first edge
            l_run *= sc;
#pragma unroll
            for (int m = 0; m < 25; ++m) acc[m] *= sc;
            m_run = lg;
            w = 1.f;
        } else {
            w = __expf(lg - m_run);                // bounded by e^THR
        }
        l_run += w;
        float wc = w * c;
#pragma unroll
        for (int m = 0; m < 25; ++m) acc[m] += w * fv[m] - wc * rv[m];
    }
    float inv = (end > beg) ? (1.f / l_run) : 0.f;
    float o[25];
#pragma unroll
    for (int m = 0; m < 25; ++m) o[m] = tanhf(acc[m] * inv);
    if (FH) {
        unsigned short* fr = (unsigned short*)Fnext + (size_t)n * HS;
#pragma unroll
        for (int j = 0; j < 3; ++j) {
            h8 hx;
#pragma unroll
            for (int m = 0; m < 8; ++m) hx.u[m] = f2h(o[8 * j + m]);
            ((h8*)(fr + 24 * sb))[j] = hx;
        }
        fr[96 + sb] = f2h(o[24]);
    } else {
        float* fr = (float*)Fnext + (size_t)n * fnstride;
        float4* f4o = (float4*)fr;
#pragma unroll
        for (int k = 0; k < 6; ++k) {
            float4 v = { o[4 * k], o[4 * k + 1], o[4 * k + 2], o[4 * k + 3] };
            f4o[6 * sb + k] = v;
        }
        fr[96 + sb] = o[24];
    }
    if (dup) {
        float* oc = outcol + (size_t)n * OUTC;
        float4* oc4 = (float4*)oc;
#pragma unroll
        for (int k = 0; k < 6; ++k) {
            float4 v = { o[4 * k], o[4 * k + 1], o[4 * k + 2], o[4 * k + 3] };
            oc4[6 * sb + k] = v;
        }
        oc[96 + sb] = o[24];
    }
    if (k3d_next) {
        const float4* w4s = (const float4*)k3d_next;
        const float4* w4n = (const float4*)(k3d_next + DD);
        float sp = o[24] * k3d_next[96 + sb];
        float np = o[24] * k3d_next[DD + 96 + sb];
#pragma unroll
        for (int k = 0; k < 6; ++k) {
            float4 ws = w4s[6 * sb + k];
            float4 wn = w4n[6 * sb + k];
            sp += o[4 * k] * ws.x + o[4 * k + 1] * ws.y + o[4 * k + 2] * ws.z + o[4 * k + 3] * ws.w;
            np += o[4 * k] * wn.x + o[4 * k + 1] * wn.y + o[4 * k + 2] * wn.z + o[4 * k + 3] * wn.w;
        }
        float sdv = quad_sum(sp);
        float ndv = quad_sum(np);
        if (sb == 0) { sdot_o[n] = sdv; ndot_o[n] = ndv; }
    }
}

extern "C" void kernel_launch(void* const* d_in, const int* in_sizes, int n_in,
                              void* d_out, int out_size, void* d_ws, size_t ws_size,
                              hipStream_t stream) {
    const float* ent_emb = (const float*)d_in[0];
    const float* rel_emb = (const float*)d_in[1];
    const float* attn_e  = (const float*)d_in[2];
    const float* attn_r  = (const float*)d_in[3];
    const int*   src     = (const int*)d_in[4];
    const int*   dst     = (const int*)d_in[5];
    const int*   erel    = (const int*)d_in[6];
    float* out = (float*)d_out;

    char* ws = (char*)d_ws;
    size_t off = 0;
    auto alloc = [&](size_t bytes) -> void* {
        void* p = ws + off;
        off = (off + bytes + 255) & ~(size_t)255;
        return p;
    };
    int*   row_ptr  = (int*)alloc((NN + 1) * sizeof(int));
    float* rel_norm = (float*)alloc((size_t)NR * DD * sizeof(float));
    float* sdotA    = (float*)alloc(NN * sizeof(float));
    float* ndotA    = (float*)alloc(NN * sizeof(float));
    float* sdotB    = (float*)alloc(NN * sizeof(float));
    float* ndotB    = (float*)alloc(NN * sizeof(float));
    float* rdot     = (float*)alloc(NR * sizeof(float));
    float* rwn      = (float*)alloc(NR * sizeof(float));
    int*   ghist    = (int*)alloc(NBIN * sizeof(int));
    int*   goffs    = (int*)alloc(NBIN * sizeof(int));
    int*   perm     = (int*)alloc(NN * sizeof(int));
    unsigned short* ent_h = (unsigned short*)alloc((size_t)NN * HS * sizeof(unsigned short));
    unsigned short* rel_h = (unsigned short*)alloc((size_t)NR * HS * sizeof(unsigned short));
    unsigned short* fA    = (unsigned short*)alloc((size_t)NN * HS * sizeof(unsigned short));
    unsigned short* fB    = (unsigned short*)alloc((size_t)NN * HS * sizeof(unsigned short));
    bool compact = (off <= ws_size);   // ~65 MB; prior rounds held >82 MB

    hipLaunchKernelGGL(k_rowptr, dim3((NN + 256) / 256), dim3(256), 0, stream,
                       dst, row_ptr, ghist);
    hipLaunchKernelGGL(k_hist, dim3((NN + 255) / 256), dim3(256), 0, stream, row_ptr, ghist);
    hipLaunchKernelGGL(k_scan, dim3(1), dim3(64), 0, stream, ghist, goffs);
    hipLaunchKernelGGL(k_scatter, dim3((NN + 255) / 256), dim3(256), 0, stream,
                       row_ptr, goffs, perm);
    hipLaunchKernelGGL(k_relnorm, dim3(NR * 64 / 256), dim3(256), 0, stream, rel_emb, rel_norm);
    if (compact) {
        hipLaunchKernelGGL(k_tohalf, dim3((NN * 4 + 255) / 256), dim3(256), 0, stream,
                           ent_emb, ent_h, NN);
        hipLaunchKernelGGL(k_tohalf, dim3((NR * 4 + 255) / 256), dim3(256), 0, stream,
                           rel_emb, rel_h, NR);
    }

    const int NODE_BLOCKS = (NN + 63) / 64;   // 64 node-groups per 256-thread block

    for (int enc = 0; enc < 2; ++enc) {
        const float* attn = (enc == 0) ? attn_e : attn_r;
        int colbase = enc * 300;

        const void* Fc; long long fs;
        if (compact) {
            const void* table = (enc == 0) ? (const void*)ent_h : (const void*)rel_h;
            hipLaunchKernelGGL(HIP_KERNEL_NAME(k_segmean<1>), dim3(NODE_BLOCKS), dim3(256), 0, stream,
                               table, (enc == 0) ? src : erel, row_ptr, perm, attn,
                               sdotA, ndotA, (void*)fA, (long long)HS,
                               out + colbase, 1);
            Fc = fA; fs = HS;
        } else {
            const void* table = (enc == 0) ? (const void*)ent_emb : (const void*)rel_emb;
            hipLaunchKernelGGL(HIP_KERNEL_NAME(k_segmean<0>), dim3(NODE_BLOCKS), dim3(256), 0, stream,
                               table, (enc == 0) ? src : erel, row_ptr, perm, attn,
                               sdotA, ndotA, (void*)(out + colbase), (long long)OUTC,
                               (float*)nullptr, 0);
            Fc = out + colbase; fs = OUTC;
        }

        for (int l = 0; l < 2; ++l) {
            int colO = colbase + (l + 1) * 100;
            const float* k3d = attn + l * 300;
            const float* k3d_next = (l == 0) ? (attn + 300) : (const float*)nullptr;
            const float* sd_in = (l == 0) ? sdotA : sdotB;
            const float* nd_in = (l == 0) ? ndotA : ndotB;
            hipLaunchKernelGGL(k_relv, dim3(NR * 64 / 256), dim3(256), 0, stream,
                               rel_norm, k3d, rdot, rwn);
            if (compact) {
                unsigned short* Fn = (l == 0) ? fB : fA;
                hipLaunchKernelGGL(HIP_KERNEL_NAME(k_layer<1>), dim3(NODE_BLOCKS), dim3(256), 0, stream,
                                   Fc, fs, rel_norm, src, erel, row_ptr, perm,
                                   sd_in, nd_in, rdot, rwn,
                                   k3d_next, sdotB, ndotB,
                                   (void*)Fn, (long long)HS,
                                   out + colO, 1);
                Fc = Fn; fs = HS;
            } else {
                hipLaunchKernelGGL(HIP_KERNEL_NAME(k_layer<0>), dim3(NODE_BLOCKS), dim3(256), 0, stream,
                                   Fc, fs, rel_norm, src, erel, row_ptr, perm,
                                   sd_in, nd_in, rdot, rwn,
                                   k3d_next, sdotB, ndotB,
                                   (void*)(out + colO), (long long)OUTC,
                                   (float*)nullptr, 0);
                Fc = out + colO; fs = OUTC;
            }
        }
    }
}

// Round 6
// 760.555 us; speedup vs baseline: 1.2648x; 1.2053x over previous
//
#include <hip/hip_runtime.h>
#include <hip/hip_fp16.h>
#include <math.h>

#define NN 100000
#define NE 1000000
#define NR 1000
#define DD 100
#define HS 104      // fp16 rel-norm row stride (halves): 208 B, 16B-aligned
#define FS2 208     // fused fp16 feature row: [enc0:104h | enc1:104h] = 416 B
#define OUTC 600
#define EPS 1e-12f
#define NBIN 64
#define RESCALE_THR 8.0f

struct __attribute__((aligned(16))) h8 { unsigned short u[8]; };

__device__ inline float h2f(unsigned short u) {
    __half_raw r; r.x = u; __half h = r; return __half2float(h);
}
__device__ inline unsigned short f2h(float f) {
    __half h = __float2half_rn(f); __half_raw r = h; return r.x;
}

__device__ inline float wave_sum(float v) {
#pragma unroll
    for (int o = 32; o > 0; o >>= 1) v += __shfl_down(v, o, 64);
    return __shfl(v, 0, 64);
}
// sum across the 4 lanes of a quad; broadcast within quad
__device__ inline float quad_sum(float v) {
    v += __shfl_xor(v, 1, 64);
    v += __shfl_xor(v, 2, 64);
    return v;
}

// row_ptr[n] = lower_bound(dst, n); dst sorted ascending. row_ptr[NN] = NE.
__global__ void k_rowptr(const int* __restrict__ dst, int* __restrict__ row_ptr,
                         int* __restrict__ ghist) {
    int n = blockIdx.x * blockDim.x + threadIdx.x;
    if (n < NBIN) ghist[n] = 0;
    if (n > NN) return;
    int lo = 0, hi = NE;
    while (lo < hi) {
        int mid = (lo + hi) >> 1;
        if (dst[mid] < n) lo = mid + 1; else hi = mid;
    }
    row_ptr[n] = lo;
}

// ---- degree counting sort: nodes of similar degree adjacent in perm.
__global__ void k_hist(const int* __restrict__ row_ptr, int* __restrict__ ghist) {
    __shared__ int lh[NBIN];
    int t = threadIdx.x;
    if (t < NBIN) lh[t] = 0;
    __syncthreads();
    int n = blockIdx.x * blockDim.x + t;
    if (n < NN) {
        int d = row_ptr[n + 1] - row_ptr[n];
        atomicAdd(&lh[min(d, NBIN - 1)], 1);
    }
    __syncthreads();
    if (t < NBIN && lh[t]) atomicAdd(&ghist[t], lh[t]);
}
__global__ void k_scan(const int* __restrict__ ghist, int* __restrict__ goffs) {
    if (threadIdx.x == 0) {
        int s = 0;
        for (int i = 0; i < NBIN; ++i) { goffs[i] = s; s += ghist[i]; }
    }
}
__global__ void k_scatter(const int* __restrict__ row_ptr, int* __restrict__ goffs,
                          int* __restrict__ perm) {
    __shared__ int lh[NBIN], base[NBIN];
    int t = threadIdx.x;
    if (t < NBIN) lh[t] = 0;
    __syncthreads();
    int n = blockIdx.x * blockDim.x + t;
    int bin = 0, rank = 0;
    if (n < NN) {
        int d = row_ptr[n + 1] - row_ptr[n];
        bin = min(d, NBIN - 1);
        rank = atomicAdd(&lh[bin], 1);
    }
    __syncthreads();
    if (t < NBIN && lh[t]) base[t] = atomicAdd(&goffs[t], lh[t]);
    __syncthreads();
    if (n < NN) perm[base[bin] + rank] = n;
}

// rel_norm (f32) + rel_nh (fp16, linear halves, stride HS); one wave per relation
__global__ void k_relnorm(const float* __restrict__ rel_emb, float* __restrict__ rel_norm,
                          unsigned short* __restrict__ rel_nh) {
    int w = (blockIdx.x * blockDim.x + threadIdx.x) >> 6;
    int lane = threadIdx.x & 63;
    if (w >= NR) return;
    const float* r = rel_emb + w * DD;
    float v0 = r[lane];
    float v1 = (lane + 64 < DD) ? r[lane + 64] : 0.f;
    float ss = wave_sum(v0 * v0 + v1 * v1);
    float sc = 1.f / fmaxf(sqrtf(ss), EPS);
    float* o = rel_norm + w * DD;
    unsigned short* oh = rel_nh + (size_t)w * HS;
    o[lane] = v0 * sc;
    oh[lane] = f2h(v0 * sc);
    if (lane + 64 < DD) {
        o[lane + 64] = v1 * sc;
        oh[lane + 64] = f2h(v1 * sc);
    }
}

// packed per-relation dots for one layer, BOTH encoders:
// rrP[r] = { <r,w_r(A)>, <r,w_r(B)>, <r,w_n(A)>, <r,w_n(B)> }
__global__ void k_relv2(const float* __restrict__ rel_norm,
                        const float* __restrict__ k3dA, const float* __restrict__ k3dB,
                        float4* __restrict__ rrP) {
    int w = (blockIdx.x * blockDim.x + threadIdx.x) >> 6;
    int lane = threadIdx.x & 63;
    if (w >= NR) return;
    const float* r = rel_norm + w * DD;
    float r0 = r[lane];
    float r1 = (lane + 64 < DD) ? r[lane + 64] : 0.f;
    float wrA0 = k3dA[2 * DD + lane], wnA0 = k3dA[DD + lane];
    float wrB0 = k3dB[2 * DD + lane], wnB0 = k3dB[DD + lane];
    float wrA1 = 0.f, wnA1 = 0.f, wrB1 = 0.f, wnB1 = 0.f;
    if (lane + 64 < DD) {
        wrA1 = k3dA[2 * DD + lane + 64]; wnA1 = k3dA[DD + lane + 64];
        wrB1 = k3dB[2 * DD + lane + 64]; wnB1 = k3dB[DD + lane + 64];
    }
    float rdA = wave_sum(r0 * wrA0 + r1 * wrA1);
    float rdB = wave_sum(r0 * wrB0 + r1 * wrB1);
    float rnA = wave_sum(r0 * wnA0 + r1 * wnA1);
    float rnB = wave_sum(r0 * wnB0 + r1 * wnB1);
    if (lane == 0) { float4 v = { rdA, rdB, rnA, rnB }; rrP[w] = v; }
}

// ---- lane mapping everywhere below: quad-lane sb owns dims [24sb..24sb+23]
// (m=0..23) plus tail dim 96+sb (m=24).

// Fused segment-mean for BOTH encoders — one NODE per quad, register acc.
// enc0 gathers ent_emb[src], enc1 gathers rel_emb[erel] (same edge walk:
// src/erel loads shared). Fuses the layer-0 node dots for both encoders.
__global__ __launch_bounds__(256) void k_segmean2(
        const float* __restrict__ ent_emb, const float* __restrict__ rel_emb,
        const int* __restrict__ src, const int* __restrict__ erel,
        const int* __restrict__ row_ptr, const int* __restrict__ perm,
        const float* __restrict__ k3dA, const float* __restrict__ k3dB,
        float2* __restrict__ sdP, float2* __restrict__ ndP,
        unsigned short* __restrict__ fused_out,   // nullable
        float* __restrict__ out) {
    int gi = (blockIdx.x * blockDim.x + threadIdx.x) >> 2;
    int sb = threadIdx.x & 3;
    if (gi >= NN) return;
    int n = perm[gi];
    int beg = row_ptr[n], end = row_ptr[n + 1];
    float a0[25] = {}, a1[25] = {};
    for (int e = beg; e < end; ++e) {
        int s = src[e];
        int t = erel[e];
        const float* er = ent_emb + (size_t)s * DD;
        const float* rr = rel_emb + (size_t)t * DD;
        const float4* e4 = (const float4*)er;
        const float4* r4 = (const float4*)rr;
#pragma unroll
        for (int k = 0; k < 6; ++k) {
            float4 v = e4[6 * sb + k];
            a0[4 * k] += v.x; a0[4 * k + 1] += v.y; a0[4 * k + 2] += v.z; a0[4 * k + 3] += v.w;
            float4 u = r4[6 * sb + k];
            a1[4 * k] += u.x; a1[4 * k + 1] += u.y; a1[4 * k + 2] += u.z; a1[4 * k + 3] += u.w;
        }
        a0[24] += er[96 + sb];
        a1[24] += rr[96 + sb];
    }
    float inv = 1.f / fmaxf((float)(end - beg), 1.f);
    float o0[25], o1[25];
#pragma unroll
    for (int m = 0; m < 25; ++m) { o0[m] = tanhf(a0[m] * inv); o1[m] = tanhf(a1[m] * inv); }
    if (fused_out) {
        unsigned short* fr = fused_out + (size_t)n * FS2;
#pragma unroll
        for (int j = 0; j < 3; ++j) {
            h8 x, y;
#pragma unroll
            for (int m = 0; m < 8; ++m) { x.u[m] = f2h(o0[8 * j + m]); y.u[m] = f2h(o1[8 * j + m]); }
            ((h8*)(fr + 24 * sb))[j] = x;
            ((h8*)(fr + 104 + 24 * sb))[j] = y;
        }
        fr[96 + sb] = f2h(o0[24]);
        fr[200 + sb] = f2h(o1[24]);
    }
    float* oc = out + (size_t)n * OUTC;
    float4* oc4 = (float4*)oc;
    float4* od4 = (float4*)(oc + 300);
#pragma unroll
    for (int k = 0; k < 6; ++k) {
        float4 v = { o0[4 * k], o0[4 * k + 1], o0[4 * k + 2], o0[4 * k + 3] };
        oc4[6 * sb + k] = v;
        float4 u = { o1[4 * k], o1[4 * k + 1], o1[4 * k + 2], o1[4 * k + 3] };
        od4[6 * sb + k] = u;
    }
    oc[96 + sb] = o0[24];
    oc[300 + 96 + sb] = o1[24];
    // fused layer-0 node dots, both encoders
    float sp0 = o0[24] * k3dA[96 + sb], np0 = o0[24] * k3dA[DD + 96 + sb];
    float sp1 = o1[24] * k3dB[96 + sb], np1 = o1[24] * k3dB[DD + 96 + sb];
    const float4* wA = (const float4*)k3dA;
    const float4* wAn = (const float4*)(k3dA + DD);
    const float4* wB = (const float4*)k3dB;
    const float4* wBn = (const float4*)(k3dB + DD);
#pragma unroll
    for (int k = 0; k < 6; ++k) {
        float4 ws = wA[6 * sb + k], wn = wAn[6 * sb + k];
        sp0 += o0[4 * k] * ws.x + o0[4 * k + 1] * ws.y + o0[4 * k + 2] * ws.z + o0[4 * k + 3] * ws.w;
        np0 += o0[4 * k] * wn.x + o0[4 * k + 1] * wn.y + o0[4 * k + 2] * wn.z + o0[4 * k + 3] * wn.w;
        float4 vs = wB[6 * sb + k], vn = wBn[6 * sb + k];
        sp1 += o1[4 * k] * vs.x + o1[4 * k + 1] * vs.y + o1[4 * k + 2] * vs.z + o1[4 * k + 3] * vs.w;
        np1 += o1[4 * k] * vn.x + o1[4 * k + 1] * vn.y + o1[4 * k + 2] * vn.z + o1[4 * k + 3] * vn.w;
    }
    sp0 = quad_sum(sp0); np0 = quad_sum(np0);
    sp1 = quad_sum(sp1); np1 = quad_sum(np1);
    if (sb == 0) {
        float2 sv = { sp0, sp1 }; sdP[n] = sv;
        float2 nv = { np0, np1 }; ndP[n] = nv;
    }
}

// Fused layer for BOTH encoders — one NODE per quad. Per edge: shared
// src/erel/packed-scalar loads, ONE fp16 rel row, two fp16 (or f32-from-out)
// feature rows; two independent defer-max online softmaxes; register acc.
// SRC=0: Fin = fused fp16 rows (stride FS2, enc1 at +104 halves).
// SRC=1: Fin = f32 rows in out (stride OUTC, enc1 at +300 floats).
template<int SRC>
__global__ __launch_bounds__(256) void k_layer2(
        const void* __restrict__ Fin,
        const unsigned short* __restrict__ rel_nh,
        const int* __restrict__ src, const int* __restrict__ erel,
        const int* __restrict__ row_ptr, const int* __restrict__ perm,
        const float2* __restrict__ sdP, const float2* __restrict__ ndP,
        const float4* __restrict__ rrP,
        const float* __restrict__ k3dA_next, const float* __restrict__ k3dB_next, // nullable
        float2* __restrict__ sdP_o, float2* __restrict__ ndP_o,
        unsigned short* __restrict__ fused_out,   // nullable
        float* __restrict__ out, int ocol) {
    int gi = (blockIdx.x * blockDim.x + threadIdx.x) >> 2;
    int sb = threadIdx.x & 3;
    if (gi >= NN) return;
    int n = perm[gi];
    int beg = row_ptr[n], end = row_ptr[n + 1];
    float2 sd2 = sdP[n];
    float acc0[25] = {}, acc1[25] = {};
    float m0 = -INFINITY, l0 = 0.f, m1 = -INFINITY, l1 = 0.f;
    for (int e = beg; e < end; ++e) {
        int s = src[e];
        int r = erel[e];
        float2 nd2 = ndP[s];
        float4 rr = rrP[r];           // {rd0, rd1, rw0, rw1}
        float f0[25], f1[25], rv[25];
        if (SRC == 0) {
            const unsigned short* fr = (const unsigned short*)Fin + (size_t)s * FS2;
            const h8* p = (const h8*)(fr + 24 * sb);
            const h8* q = (const h8*)(fr + 104 + 24 * sb);
            h8 x0 = p[0], x1 = p[1], x2 = p[2];
            h8 y0 = q[0], y1 = q[1], y2 = q[2];
#pragma unroll
            for (int m = 0; m < 8; ++m) {
                f0[m] = h2f(x0.u[m]); f0[8 + m] = h2f(x1.u[m]); f0[16 + m] = h2f(x2.u[m]);
                f1[m] = h2f(y0.u[m]); f1[8 + m] = h2f(y1.u[m]); f1[16 + m] = h2f(y2.u[m]);
            }
            f0[24] = h2f(fr[96 + sb]);
            f1[24] = h2f(fr[200 + sb]);
        } else {
            const float* fr = (const float*)Fin + (size_t)s * OUTC;
            const float4* a4 = (const float4*)fr;
            const float4* b4 = (const float4*)(fr + 300);
#pragma unroll
            for (int k = 0; k < 6; ++k) {
                float4 v = a4[6 * sb + k];
                f0[4 * k] = v.x; f0[4 * k + 1] = v.y; f0[4 * k + 2] = v.z; f0[4 * k + 3] = v.w;
                float4 u = b4[6 * sb + k];
                f1[4 * k] = u.x; f1[4 * k + 1] = u.y; f1[4 * k + 2] = u.z; f1[4 * k + 3] = u.w;
            }
            f0[24] = fr[96 + sb];
            f1[24] = fr[300 + 96 + sb];
        }
        const unsigned short* rh = rel_nh + (size_t)r * HS;
        const h8* rp = (const h8*)(rh + 24 * sb);
        h8 z0 = rp[0], z1 = rp[1], z2 = rp[2];
#pragma unroll
        for (int m = 0; m < 8; ++m) {
            rv[m] = h2f(z0.u[m]); rv[8 + m] = h2f(z1.u[m]); rv[16 + m] = h2f(z2.u[m]);
        }
        rv[24] = h2f(rh[96 + sb]);
        float p0 = f0[24] * rv[24], p1 = f1[24] * rv[24];
#pragma unroll
        for (int m = 0; m < 24; ++m) { p0 += f0[m] * rv[m]; p1 += f1[m] * rv[m]; }
        p0 = quad_sum(p0);
        p1 = quad_sum(p1);
        float c0 = 2.f * p0, c1 = 2.f * p1;
        float lg0 = sd2.x + nd2.x - c0 * rr.z + rr.x;
        float lg1 = sd2.y + nd2.y - c1 * rr.w + rr.y;
        float w0, w1;
        if (lg0 > m0 + RESCALE_THR) {
            float sc = __expf(m0 - lg0);   // 0 on first edge
            l0 *= sc;
#pragma unroll
            for (int m = 0; m < 25; ++m) acc0[m] *= sc;
            m0 = lg0; w0 = 1.f;
        } else w0 = __expf(lg0 - m0);
        if (lg1 > m1 + RESCALE_THR) {
            float sc = __expf(m1 - lg1);
            l1 *= sc;
#pragma unroll
            for (int m = 0; m < 25; ++m) acc1[m] *= sc;
            m1 = lg1; w1 = 1.f;
        } else w1 = __expf(lg1 - m1);
        l0 += w0; l1 += w1;
        float wc0 = w0 * c0, wc1 = w1 * c1;
#pragma unroll
        for (int m = 0; m < 25; ++m) {
            acc0[m] += w0 * f0[m] - wc0 * rv[m];
            acc1[m] += w1 * f1[m] - wc1 * rv[m];
        }
    }
    float i0 = (end > beg) ? (1.f / l0) : 0.f;
    float i1 = (end > beg) ? (1.f / l1) : 0.f;
    float o0[25], o1[25];
#pragma unroll
    for (int m = 0; m < 25; ++m) { o0[m] = tanhf(acc0[m] * i0); o1[m] = tanhf(acc1[m] * i1); }
    if (fused_out) {
        unsigned short* fr = fused_out + (size_t)n * FS2;
#pragma unroll
        for (int j = 0; j < 3; ++j) {
            h8 x, y;
#pragma unroll
            for (int m = 0; m < 8; ++m) { x.u[m] = f2h(o0[8 * j + m]); y.u[m] = f2h(o1[8 * j + m]); }
            ((h8*)(fr + 24 * sb))[j] = x;
            ((h8*)(fr + 104 + 24 * sb))[j] = y;
        }
        fr[96 + sb] = f2h(o0[24]);
        fr[200 + sb] = f2h(o1[24]);
    }
    float* oc = out + (size_t)n * OUTC + ocol;
    float4* oc4 = (float4*)oc;
    float4* od4 = (float4*)(oc + 300);
#pragma unroll
    for (int k = 0; k < 6; ++k) {
        float4 v = { o0[4 * k], o0[4 * k + 1], o0[4 * k + 2], o0[4 * k + 3] };
        oc4[6 * sb + k] = v;
        float4 u = { o1[4 * k], o1[4 * k + 1], o1[4 * k + 2], o1[4 * k + 3] };
        od4[6 * sb + k] = u;
    }
    oc[96 + sb] = o0[24];
    oc[300 + 96 + sb] = o1[24];
    if (k3dA_next) {
        float sp0 = o0[24] * k3dA_next[96 + sb], np0 = o0[24] * k3dA_next[DD + 96 + sb];
        float sp1 = o1[24] * k3dB_next[96 + sb], np1 = o1[24] * k3dB_next[DD + 96 + sb];
        const float4* wA = (const float4*)k3dA_next;
        const float4* wAn = (const float4*)(k3dA_next + DD);
        const float4* wB = (const float4*)k3dB_next;
        const float4* wBn = (const float4*)(k3dB_next + DD);
#pragma unroll
        for (int k = 0; k < 6; ++k) {
            float4 ws = wA[6 * sb + k], wn = wAn[6 * sb + k];
            sp0 += o0[4 * k] * ws.x + o0[4 * k + 1] * ws.y + o0[4 * k + 2] * ws.z + o0[4 * k + 3] * ws.w;
            np0 += o0[4 * k] * wn.x + o0[4 * k + 1] * wn.y + o0[4 * k + 2] * wn.z + o0[4 * k + 3] * wn.w;
            float4 vs = wB[6 * sb + k], vn = wBn[6 * sb + k];
            sp1 += o1[4 * k] * vs.x + o1[4 * k + 1] * vs.y + o1[4 * k + 2] * vs.z + o1[4 * k + 3] * vs.w;
            np1 += o1[4 * k] * vn.x + o1[4 * k + 1] * vn.y + o1[4 * k + 2] * vn.z + o1[4 * k + 3] * vn.w;
        }
        sp0 = quad_sum(sp0); np0 = quad_sum(np0);
        sp1 = quad_sum(sp1); np1 = quad_sum(np1);
        if (sb == 0) {
            float2 sv = { sp0, sp1 }; sdP_o[n] = sv;
            float2 nv = { np0, np1 }; ndP_o[n] = nv;
        }
    }
}

extern "C" void kernel_launch(void* const* d_in, const int* in_sizes, int n_in,
                              void* d_out, int out_size, void* d_ws, size_t ws_size,
                              hipStream_t stream) {
    const float* ent_emb = (const float*)d_in[0];
    const float* rel_emb = (const float*)d_in[1];
    const float* attn_e  = (const float*)d_in[2];
    const float* attn_r  = (const float*)d_in[3];
    const int*   src     = (const int*)d_in[4];
    const int*   dst     = (const int*)d_in[5];
    const int*   erel    = (const int*)d_in[6];
    float* out = (float*)d_out;

    char* ws = (char*)d_ws;
    size_t off = 0;
    auto alloc = [&](size_t bytes) -> void* {
        void* p = ws + off;
        off = (off + bytes + 255) & ~(size_t)255;
        return p;
    };
    int*    row_ptr  = (int*)alloc((NN + 1) * sizeof(int));
    float*  rel_norm = (float*)alloc((size_t)NR * DD * sizeof(float));
    unsigned short* rel_nh = (unsigned short*)alloc((size_t)NR * HS * sizeof(unsigned short));
    float2* sdPA = (float2*)alloc(NN * sizeof(float2));
    float2* ndPA = (float2*)alloc(NN * sizeof(float2));
    float2* sdPB = (float2*)alloc(NN * sizeof(float2));
    float2* ndPB = (float2*)alloc(NN * sizeof(float2));
    float4* rrP0 = (float4*)alloc(NR * sizeof(float4));
    float4* rrP1 = (float4*)alloc(NR * sizeof(float4));
    int*    ghist = (int*)alloc(NBIN * sizeof(int));
    int*    goffs = (int*)alloc(NBIN * sizeof(int));
    int*    perm  = (int*)alloc(NN * sizeof(int));
    unsigned short* fusedA = (unsigned short*)alloc((size_t)NN * FS2 * sizeof(unsigned short));
    bool planB = (off <= ws_size);   // ~46 MB
    unsigned short* fusedB = (unsigned short*)alloc((size_t)NN * FS2 * sizeof(unsigned short));
    bool planA = (off <= ws_size);   // ~88 MB

    hipLaunchKernelGGL(k_rowptr, dim3((NN + 256) / 256), dim3(256), 0, stream,
                       dst, row_ptr, ghist);
    hipLaunchKernelGGL(k_hist, dim3((NN + 255) / 256), dim3(256), 0, stream, row_ptr, ghist);
    hipLaunchKernelGGL(k_scan, dim3(1), dim3(64), 0, stream, ghist, goffs);
    hipLaunchKernelGGL(k_scatter, dim3((NN + 255) / 256), dim3(256), 0, stream,
                       row_ptr, goffs, perm);
    hipLaunchKernelGGL(k_relnorm, dim3(NR * 64 / 256), dim3(256), 0, stream,
                       rel_emb, rel_norm, rel_nh);
    hipLaunchKernelGGL(k_relv2, dim3(NR * 64 / 256), dim3(256), 0, stream,
                       rel_norm, attn_e, attn_r, rrP0);
    hipLaunchKernelGGL(k_relv2, dim3(NR * 64 / 256), dim3(256), 0, stream,
                       rel_norm, attn_e + 300, attn_r + 300, rrP1);

    const int NODE_BLOCKS = (NN + 63) / 64;   // 64 quads per 256-thread block

    // layer 0 staging: fused segment-mean for both encoders (+ layer-0 dots)
    hipLaunchKernelGGL(k_segmean2, dim3(NODE_BLOCKS), dim3(256), 0, stream,
                       ent_emb, rel_emb, src, erel, row_ptr, perm,
                       attn_e, attn_r, sdPA, ndPA,
                       planB ? fusedA : (unsigned short*)nullptr, out);

    // layer 1 (l=0): reads layer-0 feats, writes out cols 100/400 (+dots for l=1)
    if (planB) {
        hipLaunchKernelGGL(HIP_KERNEL_NAME(k_layer2<0>), dim3(NODE_BLOCKS), dim3(256), 0, stream,
                           (const void*)fusedA, rel_nh, src, erel, row_ptr, perm,
                           sdPA, ndPA, rrP0, attn_e + 300, attn_r + 300,
                           sdPB, ndPB,
                           planA ? fusedB : (unsigned short*)nullptr, out, 100);
    } else {
        hipLaunchKernelGGL(HIP_KERNEL_NAME(k_layer2<1>), dim3(NODE_BLOCKS), dim3(256), 0, stream,
                           (const void*)out, rel_nh, src, erel, row_ptr, perm,
                           sdPA, ndPA, rrP0, attn_e + 300, attn_r + 300,
                           sdPB, ndPB,
                           (unsigned short*)nullptr, out, 100);
    }

    // layer 2 (l=1): reads layer-1 feats, writes out cols 200/500 (no dots)
    if (planA) {
        hipLaunchKernelGGL(HIP_KERNEL_NAME(k_layer2<0>), dim3(NODE_BLOCKS), dim3(256), 0, stream,
                           (const void*)fusedB, rel_nh, src, erel, row_ptr, perm,
                           sdPB, ndPB, rrP1, (const float*)nullptr, (const float*)nullptr,
                           sdPB, ndPB,
                           (unsigned short*)nullptr, out, 200);
    } else {
        hipLaunchKernelGGL(HIP_KERNEL_NAME(k_layer2<1>), dim3(NODE_BLOCKS), dim3(256), 0, stream,
                           (const void*)(out + 100), rel_nh, src, erel, row_ptr, perm,
                           sdPB, ndPB, rrP1, (const float*)nullptr, (const float*)nullptr,
                           sdPB, ndPB,
                           (unsigned short*)nullptr, out, 200);
    }
}